// Round 6
// baseline (120.838 us; speedup 1.0000x reference)
//
#include <hip/hip_runtime.h>

// Problem constants (fixed by reference)
#define BS      16
#define CIN     32
#define COUT    64
#define OUT_DIM 1024
#define RS4     1024           // float4 per (.,c) row of length 4096 floats

// v9-DIAG: v8 body, repeated 4x with laundered addresses, single dispatch.
// Purpose: v3-v8 (4 structures, 2.6x byte spread, 1.5x occupancy spread)
// all land at 20-24 us while every static floor says <=8 us -- and the
// kernel has been invisible in rocprof (top-5 cutoff ~43 us) for 3 rounds.
// Theory to test: the harness's per-iteration 256 MiB fill (= L3 size)
// leaves L3 100% dirty; our 44 MB of cold reads evict dirty victims ->
// ~48 MB of writeback drains to HBM DURING the kernel -> composite ~96 MB
// = 15.2 us floor, structure-independent (explains the tie).
// The 4x repeat makes the dispatch ~45-50 us (visible) and discriminates:
//   writeback true  -> WRITE_SIZE 50-70 MB (>> 16), FETCH 45-65 MB
//   writeback false -> WRITE_SIZE ~16 MB; FETCH 176 MB => L3 not retaining,
//                      or FETCH ~50 MB + dur ~4x20 => latency-bound (read
//                      VALUBusy / OccupancyPercent).
// Address laundering (off=0 passed through asm volatile) defeats load-CSE /
// dead-store-elim across reps (guide rule #17) so every rep re-traffics
// memory. Output is written 4x with identical values -> correctness intact.
__global__ __launch_bounds__(256, 6) void nolc1d_kernel(
    const float* __restrict__ x,
    const float* __restrict__ w,
    float* __restrict__ out)
{
    // bid = xcd + 8*j ; j = og | bs<<4 | pghi<<6  -> pg = xcd + 8*pghi
    const int bid = blockIdx.x;
    const int xcd = bid & 7;
    const int j   = bid >> 3;
    const int og  = j & 15;                 // o-group 0..15 (4 o each)
    const int bs  = (j >> 4) & 3;           // b-group 0..3  (4 b each)
    const int pg  = xcd + 8 * (j >> 6);     // patch-group 0..31 (32 p each)
    const int o0  = og * 4;
    const int b0  = bs * 4;

    const int t    = threadIdx.x;
    const int lane = t & 63;
    const int wv   = t >> 6;                // wave 0..3
    const int cs   = t >> 5;                // c-split 0..7 (c % 8 == cs)
    const int pp   = t & 31;                // patch (float4 col) in block

    const float4* __restrict__ x4 = (const float4*)x;
    const float4* __restrict__ w4 = (const float4*)w;

    __shared__ float red[4][4][4][32];

    const float scale = 0.17677669529663687f;  // 1/sqrt(32)

    #pragma unroll 1
    for (int rep = 0; rep < 4; ++rep) {
        // Launder a zero through an opaque asm so addresses differ (to the
        // compiler) each rep: blocks CSE of loads and DSE of stores.
        int off = 0;
        asm volatile("" : "+v"(off));
        const int pf0 = pg * 32 + off;      // float4 column base (runtime 0)

        float acc[4][4] = {};               // [bi][o]

        #pragma unroll 1
        for (int k = 0; k < 4; ++k) {
            const int c = cs + 8 * k;
            float4 xv[4];
            #pragma unroll
            for (int bi = 0; bi < 4; ++bi)
                xv[bi] = x4[((b0 + bi) * CIN + c) * RS4 + pf0 + pp];
            #pragma unroll
            for (int o = 0; o < 4; ++o) {
                const float4 wq = w4[((o0 + o) * CIN + c) * RS4 + pf0 + pp];
                #pragma unroll
                for (int bi = 0; bi < 4; ++bi)
                    acc[bi][o] += xv[bi].x * wq.x + xv[bi].y * wq.y +
                                  xv[bi].z * wq.z + xv[bi].w * wq.w;
            }
        }

        // c-reduction stage 1: lane^32 holds cs^1 (same pp) -> 2-way.
        #pragma unroll
        for (int bi = 0; bi < 4; ++bi)
            #pragma unroll
            for (int o = 0; o < 4; ++o)
                acc[bi][o] += __shfl_xor(acc[bi][o], 32, 64);

        // c-reduction stage 2: 4-way over waves via LDS.
        if (rep) __syncthreads();   // reps 2..4: writers done reading red
        if (lane < 32) {
            #pragma unroll
            for (int bi = 0; bi < 4; ++bi)
                #pragma unroll
                for (int o = 0; o < 4; ++o)
                    red[wv][bi][o][pp] = acc[bi][o];
        }
        __syncthreads();

        #pragma unroll
        for (int rr = 0; rr < 2; ++rr) {
            const int idx = t + 256 * rr;   // 0..511 = (b*4 + o)*32 + p2
            const int b   = idx >> 7;
            const int o   = (idx >> 5) & 3;
            const int p2  = idx & 31;
            const float s = red[0][b][o][p2] + red[1][b][o][p2] +
                            red[2][b][o][p2] + red[3][b][o][p2];
            out[((size_t)(b0 + b) * COUT + o0 + o) * OUT_DIM
                + (size_t)(pg * 32 + off) + p2] = s * scale;
        }
    }
}

extern "C" void kernel_launch(void* const* d_in, const int* in_sizes, int n_in,
                              void* d_out, int out_size, void* d_ws, size_t ws_size,
                              hipStream_t stream) {
    const float* x = (const float*)d_in[0];   // [16][32][4096] fp32
    const float* w = (const float*)d_in[1];   // [64][32][4096] fp32
    float* out = (float*)d_out;               // [16][64][1024] fp32

    nolc1d_kernel<<<dim3(2048), dim3(256), 0, stream>>>(x, w, out);
}

// Round 9
// 87.742 us; speedup vs baseline: 1.3772x; 1.3772x over previous
//
#include <hip/hip_runtime.h>

// Problem constants (fixed by reference)
#define BS      16
#define CIN     32
#define COUT    64
#define OUT_DIM 1024
#define RS4     1024           // float4 per (.,c) row of length 4096 floats

// out[b,o,p] = (1/sqrt(32)) * sum_{c,k} x[b,c,4p+k] * w[o,c,4p+k]
//
// v11 = v10 with the LDS sizing bug fixed: the staged w slice is
// 4o x 32c x 32 float4 = 4096 float4 = 64 KB; v10 declared ws[2048] (32 KB)
// so all c>=16 reads were OOB garbage (absmax 7.0). Structure unchanged:
//
//   - two-port delivery (v9-DIAG: family was bound on VGPR-delivered bytes
//     through the single L1 port, ~1 MB/CU => 13 us warm): w through the
//     LDS port (512 KB/CU), x through L1 (512 KB/CU), overlapped.
//   - each block stages its w slice ONCE via global_load_lds (one barrier,
//     no double-buffer pipeline), then a barrier-free main loop.
//   - block covers ALL 16 b: w staged exactly once globally.
//   - 64 KB LDS/block -> 2 blocks/CU; launch_bounds(1024,8) caps 64 VGPR
//     (live ~50) -> 32 waves/CU resident.
// Grid = 16 og x 32 pg = 512. XCD swizzle: all 16 og-blocks of a pg (which
// share its 256 KB x slice) land on one XCD -> x redundancy L2-served.
__global__ __launch_bounds__(1024, 8) void nolc1d_kernel(
    const float* __restrict__ x,
    const float* __restrict__ w,
    float* __restrict__ out)
{
    const int bid = blockIdx.x;
    const int xcd = bid & 7;
    const int j   = bid >> 3;
    const int og  = j & 15;                 // o-group 0..15 (4 o each)
    const int pg  = xcd + 8 * (j >> 4);     // patch-group 0..31 (32 p each)
    const int o0  = og * 4;
    const int pf0 = pg * 32;                // float4 column base

    const int t    = threadIdx.x;
    const int lane = t & 63;
    const int wv   = t >> 6;                // wave 0..15
    const int g    = t >> 8;                // b-quad 0..3 (b = 4g+bi)
    const int cs   = (t >> 5) & 7;          // c-split 0..7 (c % 8 == cs)
    const int pp   = t & 31;                // patch (float4 col) in block

    // w slice [c][o][pp] float4 = 4096 float4 = 64 KB (the v10 bug: 2048).
    // First 2048 entries reused as the reduction buffer after the loop.
    __shared__ float4 ws[4096];

    const float4* __restrict__ x4 = (const float4*)x;
    const float4* __restrict__ w4 = (const float4*)w;

    // ---- stage: 64 KB = 64 segments of 1 KB (16 waves x 4 insts).
    // Segment s covers rows 2s,2s+1 (row = c*4+o, 32 float4 each); LDS dest
    // is wave-uniform base + lane*16 (linear, as global_load_lds requires);
    // global source per-lane: half-wave h reads row 2s+h, lanes q=0..31.
    {
        const int half = lane >> 5;
        const int q    = lane & 31;
        #pragma unroll
        for (int i = 0; i < 4; ++i) {
            const int s   = wv * 4 + i;         // 0..63
            const int row = 2 * s + half;       // 0..127 = c*4 + o
            const int cc  = row >> 2;
            const int oo  = row & 3;
            const float4* src =
                &w4[((o0 + oo) * CIN + cc) * RS4 + pf0 + q];
            float4* dst = &ws[s * 64];          // lane-invariant base
            __builtin_amdgcn_global_load_lds(
                (const __attribute__((address_space(1))) void*)src,
                (__attribute__((address_space(3))) void*)dst,
                16, 0, 0);
        }
    }
    __syncthreads();   // drains vmcnt -> ws fully staged

    // ---- barrier-free main loop: this thread's 4 c's (c = cs + 8k).
    // x from L1 (4 float4 in flight/wave), w from LDS (2 contiguous 512 B
    // runs per wave -> conflict-free).
    float acc[4][4] = {};                   // [bi][o]
    #pragma unroll 1
    for (int k = 0; k < 4; ++k) {
        const int c  = cs + 8 * k;
        const int xo = c * RS4 + pf0 + pp;
        const float4 xv0 = x4[(size_t)((4 * g + 0) * CIN) * RS4 + xo];
        const float4 xv1 = x4[(size_t)((4 * g + 1) * CIN) * RS4 + xo];
        const float4 xv2 = x4[(size_t)((4 * g + 2) * CIN) * RS4 + xo];
        const float4 xv3 = x4[(size_t)((4 * g + 3) * CIN) * RS4 + xo];
        #pragma unroll
        for (int o = 0; o < 4; ++o) {
            const float4 wq = ws[(c * 4 + o) * 32 + pp];
            acc[0][o] += xv0.x * wq.x + xv0.y * wq.y +
                         xv0.z * wq.z + xv0.w * wq.w;
            acc[1][o] += xv1.x * wq.x + xv1.y * wq.y +
                         xv1.z * wq.z + xv1.w * wq.w;
            acc[2][o] += xv2.x * wq.x + xv2.y * wq.y +
                         xv2.z * wq.z + xv2.w * wq.w;
            acc[3][o] += xv3.x * wq.x + xv3.y * wq.y +
                         xv3.z * wq.z + xv3.w * wq.w;
        }
    }

    // ---- c-reduction stage 1: lane^32 holds cs^1 (same g, pp) -> 2-way.
    #pragma unroll
    for (int bi = 0; bi < 4; ++bi)
        #pragma unroll
        for (int o = 0; o < 4; ++o)
            acc[bi][o] += __shfl_xor(acc[bi][o], 32, 64);

    // ---- c-reduction stage 2: 4-way over csh = cs>>1 = wv&3 via LDS
    // (reuse ws[0..2047]; all w-reads completed before the barrier).
    __syncthreads();
    const int csh = wv & 3;
    if (lane < 32) {
        #pragma unroll
        for (int o = 0; o < 4; ++o)
            ws[csh * 512 + (g * 4 + o) * 32 + pp] =
                make_float4(acc[0][o], acc[1][o], acc[2][o], acc[3][o]);
    }
    __syncthreads();

    const float scale = 0.17677669529663687f;  // 1/sqrt(32)
    if (t < 512) {
        // t = (g2*4 + oo)*32 + p2 ; float4 components = b = 4*g2 + 0..3
        const float4 a = ws[t];
        const float4 b = ws[t + 512];
        const float4 c = ws[t + 1024];
        const float4 d = ws[t + 1536];
        const int g2 = t >> 7;
        const int oo = (t >> 5) & 3;
        const int p2 = t & 31;
        const size_t p = (size_t)pg * 32 + p2;
        out[((size_t)(4 * g2 + 0) * COUT + o0 + oo) * OUT_DIM + p] =
            (a.x + b.x + c.x + d.x) * scale;
        out[((size_t)(4 * g2 + 1) * COUT + o0 + oo) * OUT_DIM + p] =
            (a.y + b.y + c.y + d.y) * scale;
        out[((size_t)(4 * g2 + 2) * COUT + o0 + oo) * OUT_DIM + p] =
            (a.z + b.z + c.z + d.z) * scale;
        out[((size_t)(4 * g2 + 3) * COUT + o0 + oo) * OUT_DIM + p] =
            (a.w + b.w + c.w + d.w) * scale;
    }
}

extern "C" void kernel_launch(void* const* d_in, const int* in_sizes, int n_in,
                              void* d_out, int out_size, void* d_ws, size_t ws_size,
                              hipStream_t stream) {
    const float* x = (const float*)d_in[0];   // [16][32][4096] fp32
    const float* w = (const float*)d_in[1];   // [64][32][4096] fp32
    float* out = (float*)d_out;               // [16][64][1024] fp32

    nolc1d_kernel<<<dim3(512), dim3(1024), 0, stream>>>(x, w, out);
}

// Round 10
// 86.161 us; speedup vs baseline: 1.4025x; 1.0184x over previous
//
#include <hip/hip_runtime.h>

// Problem constants (fixed by reference)
#define CIN     32
#define COUT    64
#define OUT_DIM 1024
#define RS4     1024           // float4 per (.,c) row (4096 floats)

// out[b,o,p] = (1/sqrt(32)) * sum_{c,k} x[b,c,4p+k] * w[o,c,4p+k]
//
// v12: kill the x L2 re-read invariant. v3..v11 all kept o-tile <= 8, so x
// was pulled ~16x through L2 (~128 MB); v9-DIAG's warm rep (13 us for
// ~160 MB L2 traffic = 12.3 TB/s achieved) says that is the shared wall --
// and it's the one parameter never varied. v12: o-tile 16, patch-tile 4:
// the WHOLE block working set (w 32 KB + x 32 KB) is staged into LDS
// exactly once via global_load_lds (one barrier), all compute from LDS.
//   - x L2 traffic 128 -> 32 MB; w 32 MB once; total ~68 MB (~5.5 us).
//   - HBM ~44-64 MB (~7-10 us) = the new floor; LDS compute (~5 us/CU,
//     2 B/MAC register-tiled) hides under staging via 2 resident blocks.
//   - per-wave LDS reads: x = 512 B contiguous (conflict-free), w = 2-way
//     same-address broadcast (free). Stage sources are whole 64 B lines.
// Grid 1024 = 4 og x 256 pgq; swizzle xcd = pgq>>5: the 4 og-blocks sharing
// an x-slice AND consecutive pgq (out write-merge) share an XCD; per-XCD x
// working set 4 MB = L2 size.
__global__ __launch_bounds__(512, 4) void nolc1d_kernel(
    const float* __restrict__ x,
    const float* __restrict__ w,
    float* __restrict__ out)
{
    // bid = (pgq>>5) + 8*(og + 4*(pgq&31))  [bijective over 1024]
    const int bid = blockIdx.x;
    const int xcd = bid & 7;
    const int m   = bid >> 3;
    const int og  = m & 3;                  // o-group 0..3 (16 o each)
    const int pgq = xcd * 32 + (m >> 2);    // patch-quad 0..255 (4 p each)
    const int o0  = og * 16;
    const int pf4 = pgq * 4;                // float4 column base

    const int t    = threadIdx.x;           // = oq*128 + g*32 + p*8 + cs
    const int lane = t & 63;
    const int wv   = t >> 6;                // wave 0..7
    const int cs   = t & 7;                 // c-split (c % 8 == cs)
    const int p    = (t >> 3) & 3;          // patch within quad
    const int g    = (t >> 5) & 3;          // b-quad (b = 4g+bi)
    const int oq   = t >> 7;                // o-quad within tile (o=4oq+oi)

    // [(row)*4 + q] float4, row = ol*32+c (w) or b*32+c (x); q = patch.
    __shared__ float4 wls[2048];            // 32 KB
    __shared__ float4 xls[2048];            // 32 KB (reused as epilogue buf)

    const float4* __restrict__ x4 = (const float4*)x;
    const float4* __restrict__ w4 = (const float4*)w;

    // ---- stage both operands: 64 segments of 1 KB (8 waves x 8 instrs).
    // Segment s covers rows 16s..16s+15 (64 B each); LDS dest linear
    // (wave-uniform base + lane*16); source: lane L -> row 16s+(L>>2),
    // q = L&3 -> 16 full 64 B lines per instruction.
    {
        const int r = lane >> 2;            // 0..15
        const int q = lane & 3;             // 0..3
        #pragma unroll
        for (int i = 0; i < 4; ++i) {
            const int s  = wv * 4 + i;      // 0..31
            const int rr = s * 16 + r;      // 0..511 = hi*32 + c
            const int hi = rr >> 5;         // ol (w) / b (x)
            const int cc = rr & 31;
            const float4* srcw =
                &w4[((size_t)(o0 + hi) * CIN + cc) * RS4 + pf4 + q];
            __builtin_amdgcn_global_load_lds(
                (const __attribute__((address_space(1))) void*)srcw,
                (__attribute__((address_space(3))) void*)&wls[s * 64],
                16, 0, 0);
            const float4* srcx =
                &x4[((size_t)hi * CIN + cc) * RS4 + pf4 + q];
            __builtin_amdgcn_global_load_lds(
                (const __attribute__((address_space(1))) void*)srcx,
                (__attribute__((address_space(3))) void*)&xls[s * 64],
                16, 0, 0);
        }
    }
    __syncthreads();   // drains vmcnt -> both tiles staged

    // ---- compute: this thread's 4 c's (c = cs + 8j), all from LDS.
    float acc[4][4] = {};                   // [bi][oi]
    #pragma unroll 2
    for (int j = 0; j < 4; ++j) {
        const int c = cs + 8 * j;
        float4 xv[4], wq[4];
        #pragma unroll
        for (int bi = 0; bi < 4; ++bi)
            xv[bi] = xls[((g * 4 + bi) * 32 + c) * 4 + p];
        #pragma unroll
        for (int oi = 0; oi < 4; ++oi)
            wq[oi] = wls[((oq * 4 + oi) * 32 + c) * 4 + p];
        #pragma unroll
        for (int bi = 0; bi < 4; ++bi)
            #pragma unroll
            for (int oi = 0; oi < 4; ++oi)
                acc[bi][oi] += xv[bi].x * wq[oi].x + xv[bi].y * wq[oi].y +
                               xv[bi].z * wq[oi].z + xv[bi].w * wq[oi].w;
    }

    // ---- 8-way c-reduction over cs (lane bits 0..2): butterfly shfl.
    #pragma unroll
    for (int d = 1; d <= 4; d <<= 1)
        #pragma unroll
        for (int bi = 0; bi < 4; ++bi)
            #pragma unroll
            for (int oi = 0; oi < 4; ++oi)
                acc[bi][oi] += __shfl_xor(acc[bi][oi], d, 64);

    // ---- epilogue: repack via LDS (reuse xls) for coalesced float4 out.
    __syncthreads();   // all compute-phase LDS reads complete
    float* red = (float*)xls;               // 1024 floats used
    const float scale = 0.17677669529663687f;  // 1/sqrt(32)
    if (cs == 0) {
        #pragma unroll
        for (int bi = 0; bi < 4; ++bi)
            #pragma unroll
            for (int oi = 0; oi < 4; ++oi)
                red[((g * 4 + bi) * 16 + (oq * 4 + oi)) * 4 + p] =
                    acc[bi][oi] * scale;
    }
    __syncthreads();

    if (t < 256) {
        // t = b*16 + ol ; float4 = out[b][o0+ol][pgq*4 .. pgq*4+3]
        const int b  = t >> 4;
        const int ol = t & 15;
        ((float4*)out)[((size_t)b * COUT + o0 + ol) * (OUT_DIM / 4) + pgq] =
            ((float4*)red)[t];
    }
}

extern "C" void kernel_launch(void* const* d_in, const int* in_sizes, int n_in,
                              void* d_out, int out_size, void* d_ws, size_t ws_size,
                              hipStream_t stream) {
    const float* x = (const float*)d_in[0];   // [16][32][4096] fp32
    const float* w = (const float*)d_in[1];   // [64][32][4096] fp32
    float* out = (float*)d_out;               // [16][64][1024] fp32

    nolc1d_kernel<<<dim3(1024), dim3(512), 0, stream>>>(x, w, out);
}

// Round 11
// 83.627 us; speedup vs baseline: 1.4450x; 1.0303x over previous
//
#include <hip/hip_runtime.h>

// Problem constants (fixed by reference)
#define CIN     32
#define COUT    64
#define OUT_DIM 1024
#define RS4     1024           // float4 per (.,c) row (4096 floats)

// out[b,o,p] = (1/sqrt(32)) * sum_{c,k} x[b,c,4p+k] * w[o,c,4p+k]
//
// v13: v12's bytes (everything staged into LDS exactly once, o-tile 16,
// all 16 b) but PIPELINED. v12's timeline: 2 resident blocks stage (5.1 us,
// HBM busy) then compute (2.6 us, HBM idle), x2 generations = ~19 us with
// ~60% HBM duty -- phases never overlapped. v13: one block per CU iterates
// its (og, 16-patch) tile over 4 c-chunks with double-buffered LDS
// (2 x (w 32 KB + x 32 KB) = 128 KB):
//
//   stage(0); barrier; for ci: { stage(ci+1) -> other buf; compute(ci)
//   from LDS only; barrier (vmcnt drain = pipeline handoff) }
//
// The v6 trap (FIFO vmcnt coupling compute's global x-loads to the next
// stage) is structurally absent: the compute phase issues ZERO global
// loads. stage(ci+1) delivers from HBM while compute(ci) runs; per iter
// compute ~1.3 us (LDS pipe) vs delivery ~1.6-2 us -> HBM duty >90%.
// Iterating over c (not patches): acc carries across iters, a single 2-way
// shfl reduction + epilogue at the end; stage rows are 256 B contiguous.
// Grid 256 = 4 og x 64 pc; swizzle: 4 og-siblings (sharing a pc's x slice)
// + 8 consecutive pc per XCD -> x og-redundancy is XCD-L2-served.
__global__ __launch_bounds__(512, 2) void nolc1d_kernel(
    const float* __restrict__ x,
    const float* __restrict__ w,
    float* __restrict__ out)
{
    const int bid = blockIdx.x;
    const int xcd = bid & 7;
    const int m   = bid >> 3;               // 0..31
    const int og  = m & 3;                  // o-group 0..3 (16 o each)
    const int pc  = xcd * 8 + (m >> 2);     // patch-chunk 0..63 (16 p each)
    const int o0  = og * 16;
    const int pf0 = pc * 16;                // f4 (=patch) column base

    const int t    = threadIdx.x;           // = oq*128 + g*32 + cs*16 + p
    const int lane = t & 63;
    const int wv   = t >> 6;                // wave 0..7
    const int p    = t & 15;                // patch within chunk
    const int cs   = (t >> 4) & 1;          // c-split (2-way)
    const int g    = (t >> 5) & 3;          // b-quad (b = 4g+bi)
    const int oq   = t >> 7;                // o-quad (o = o0+4oq+oi)

    // [buf][(hi*8 + cl)*16 + q]: hi = ol (w) / b (x), cl = c within chunk,
    // q = f4 column. 2048 f4 = 32 KB each; total 128 KB.
    __shared__ float4 wls[2][2048];
    __shared__ float4 xls[2][2048];

    const float4* __restrict__ x4 = (const float4*)x;
    const float4* __restrict__ w4 = (const float4*)w;

    const int r4 = lane >> 4;               // row within 4-row segment
    const int q  = lane & 15;

    // Stage c-chunk ci (c = 8ci..8ci+7) into buffer `buf`: per operand
    // 128 rows x 256 B = 32 KB = 32 wave-instrs (8 waves x 4). LDS dest is
    // wave-uniform base + lane*16 (linear); source rows 256 B contiguous.
    auto stage = [&](int buf, int ci) {
        #pragma unroll
        for (int i = 0; i < 4; ++i) {
            const int s   = wv * 4 + i;     // segment 0..31 (4 rows each)
            const int row = s * 4 + r4;     // 0..127 = hi*8 + cl
            const int hi  = row >> 3;
            const int c   = ci * 8 + (row & 7);
            const float4* srcw =
                &w4[((o0 + hi) * CIN + c) * RS4 + pf0 + q];
            __builtin_amdgcn_global_load_lds(
                (const __attribute__((address_space(1))) void*)srcw,
                (__attribute__((address_space(3))) void*)&wls[buf][s * 64],
                16, 0, 0);
            const float4* srcx =
                &x4[(hi * CIN + c) * RS4 + pf0 + q];
            __builtin_amdgcn_global_load_lds(
                (const __attribute__((address_space(1))) void*)srcx,
                (__attribute__((address_space(3))) void*)&xls[buf][s * 64],
                16, 0, 0);
        }
    };

    float acc[4][4] = {};                   // [bi][oi], carried over ci

    stage(0, 0);
    __syncthreads();   // vmcnt drain: buffer 0 staged

    #pragma unroll 1
    for (int ci = 0; ci < 4; ++ci) {
        if (ci < 3) stage((ci + 1) & 1, ci + 1);   // async prefetch
        const int buf = ci & 1;
        // compute: LDS only. This thread's c's: cl = cs*4 + jj.
        // w reads: 2 rows/wave, 2-way same-address broadcast (free);
        // x reads: 4 rows/wave, 256 B contiguous per 16 lanes -> no
        // bank conflicts.
        #pragma unroll
        for (int jj = 0; jj < 4; ++jj) {
            const int cl = cs * 4 + jj;
            float4 xv[4], wq[4];
            #pragma unroll
            for (int bi = 0; bi < 4; ++bi)
                xv[bi] = xls[buf][((g * 4 + bi) * 8 + cl) * 16 + p];
            #pragma unroll
            for (int oi = 0; oi < 4; ++oi)
                wq[oi] = wls[buf][((oq * 4 + oi) * 8 + cl) * 16 + p];
            #pragma unroll
            for (int bi = 0; bi < 4; ++bi)
                #pragma unroll
                for (int oi = 0; oi < 4; ++oi)
                    acc[bi][oi] += xv[bi].x * wq[oi].x + xv[bi].y * wq[oi].y +
                                   xv[bi].z * wq[oi].z + xv[bi].w * wq[oi].w;
        }
        // readers done with buf (next iter's stage overwrites it) AND
        // prefetch for ci+1 drained (vmcnt 0). Not needed after last iter.
        if (ci < 3) __syncthreads();
    }

    // c-reduction: partner t^16 (same oq,g,p; cs^1) holds the other half.
    #pragma unroll
    for (int bi = 0; bi < 4; ++bi)
        #pragma unroll
        for (int oi = 0; oi < 4; ++oi)
            acc[bi][oi] += __shfl_xor(acc[bi][oi], 16, 64);

    const float scale = 0.17677669529663687f;  // 1/sqrt(32)
    if (cs == 0) {
        // lanes p=0..15 -> 64 B contiguous store per (bi,oi) per 16-lane
        // group; single writer per line.
        #pragma unroll
        for (int bi = 0; bi < 4; ++bi)
            #pragma unroll
            for (int oi = 0; oi < 4; ++oi)
                out[((size_t)(4 * g + bi) * COUT + o0 + 4 * oq + oi) * OUT_DIM
                    + pf0 + p] = acc[bi][oi] * scale;
    }
}

extern "C" void kernel_launch(void* const* d_in, const int* in_sizes, int n_in,
                              void* d_out, int out_size, void* d_ws, size_t ws_size,
                              hipStream_t stream) {
    const float* x = (const float*)d_in[0];   // [16][32][4096] fp32
    const float* w = (const float*)d_in[1];   // [64][32][4096] fp32
    float* out = (float*)d_out;               // [16][64][1024] fp32

    nolc1d_kernel<<<dim3(256), dim3(512), 0, stream>>>(x, w, out);
}